// Round 23
// baseline (126.739 us; speedup 1.0000x reference)
//
#include <hip/hip_runtime.h>
#include <hip/hip_bf16.h>

typedef __bf16 bf16x8 __attribute__((ext_vector_type(8)));
typedef __bf16 bf16x4 __attribute__((ext_vector_type(4)));
typedef float  f32x4  __attribute__((ext_vector_type(4)));
typedef short  short4v __attribute__((ext_vector_type(4)));

#define MFMA_16x16x32(a,b,c) __builtin_amdgcn_mfma_f32_16x16x32_bf16((a),(b),(c),0,0,0)

#if __has_builtin(__builtin_amdgcn_mfma_f32_16x16x16_bf16)
__device__ inline f32x4 MFMA16(bf16x4 a, bf16x4 b, f32x4 c){
  return __builtin_amdgcn_mfma_f32_16x16x16_bf16(a, b, c, 0, 0, 0);
}
#elif __has_builtin(__builtin_amdgcn_mfma_f32_16x16x16bf16_1k)
__device__ inline f32x4 MFMA16(bf16x4 a, bf16x4 b, f32x4 c){
  return __builtin_amdgcn_mfma_f32_16x16x16bf16_1k(
      __builtin_bit_cast(short4v, a), __builtin_bit_cast(short4v, b), c, 0, 0, 0);
}
#else
__device__ inline f32x4 MFMA16(bf16x4 a, bf16x4 b, f32x4 c){
  f32x4 d;
  asm volatile("v_mfma_f32_16x16x16_bf16 %0, %1, %2, %3"
               : "=v"(d) : "v"(a), "v"(b), "v"(c));
  return d;
}
#endif

// raw hardware exp2 (r13: libm exp2f was ~half of attn VALU)
#if __has_builtin(__builtin_amdgcn_exp2f)
#define EXP2(x) __builtin_amdgcn_exp2f(x)
#else
extern "C" __device__ float __ocml_native_exp2_f32(float);
#define EXP2(x) __ocml_native_exp2_f32(x)
#endif

#if __has_builtin(__builtin_amdgcn_global_load_lds)
#define HAS_GLDS 1
__device__ inline void glds16(const __bf16* g, __bf16* l){
  __builtin_amdgcn_global_load_lds(
      (const __attribute__((address_space(1))) unsigned int*)g,
      (__attribute__((address_space(3))) unsigned int*)l, 16, 0, 0);
}
#else
#define HAS_GLDS 0
#endif

static constexpr int DM = 768;
static constexpr int NH = 12;
static constexpr int HD = 64;
static constexpr int BB = 2;
static constexpr int SS = 2048;
static constexpr int NR = BB*SS;       // 4096 rows (b,s)
static constexpr int NC = 3*DM;        // 2304 qkv output cols
// logits in log2 domain: fold 1/sqrt(64) * log2(e) into Wq,bq
static constexpr float SCALEQ = 0.125f * 1.4426950408889634f;

__device__ inline int xcd_swz(int b, int n){
  return (n % 8 == 0) ? (b % 8) * (n >> 3) + (b >> 3) : b;
}

// ---------------- fused prep kernel (one launch) -----------
static constexpr int PB_X = NR*DM/(4*256);   // 3072
static constexpr int PB_W = 3*12*12;         // 432
static constexpr int PB_O = 12*12;           // 144
static constexpr int PB_B = (NC+255)/256;    // 9
__global__ __launch_bounds__(256) void k_prep(const float* __restrict__ x,
    const float* __restrict__ Wq, const float* __restrict__ Wk,
    const float* __restrict__ Wv, const float* __restrict__ bq,
    const float* __restrict__ bk, const float* __restrict__ bv,
    const float* __restrict__ Wo,
    __bf16* __restrict__ xb, __bf16* __restrict__ Wt,
    __bf16* __restrict__ WoT, float* __restrict__ bqkv)
{
  __shared__ float tile[64][65];
  const int blk = blockIdx.x, tid = threadIdx.x;
  if (blk < PB_X){
    int i = blk*256 + tid;
    float4 v = reinterpret_cast<const float4*>(x)[i];
    bf16x4 o; o[0]=(__bf16)v.x; o[1]=(__bf16)v.y; o[2]=(__bf16)v.z; o[3]=(__bf16)v.w;
    reinterpret_cast<bf16x4*>(xb)[i] = o;
  } else if (blk < PB_X + PB_W){
    int b2 = blk - PB_X;
    int dt = b2 % 12, h = (b2/12) % 12, m = b2/144;
    const float* W = (m==0)?Wq:((m==1)?Wk:Wv);
    float scale = (m==0)?SCALEQ:1.0f;
    int tx = tid & 63, ty = tid >> 6;
    #pragma unroll
    for (int i=0;i<16;i++){
      int dl = ty*16+i;
      tile[dl][tx] = W[(h*DM + dt*64 + dl)*HD + tx];
    }
    __syncthreads();
    #pragma unroll
    for (int i=0;i<16;i++){
      int e = ty*16+i;
      Wt[(size_t)(m*DM + h*HD + e)*DM + dt*64 + tx] = (__bf16)(tile[tx][e]*scale);
    }
  } else if (blk < PB_X + PB_W + PB_O){
    int b2 = blk - PB_X - PB_W;
    int dt = b2 % 12, ct = b2/12;
    int tx = tid & 63, ty = tid >> 6;
    #pragma unroll
    for (int i=0;i<16;i++){
      int dl = ty*16+i;
      tile[dl][tx] = Wo[(dt*64+dl)*DM + ct*64 + tx];
    }
    __syncthreads();
    #pragma unroll
    for (int i=0;i<16;i++){
      int cl = ty*16+i;
      WoT[(size_t)(ct*64+cl)*DM + dt*64 + tx] = (__bf16)tile[tx][cl];
    }
  } else {
    int c = (blk - PB_X - PB_W - PB_O)*256 + tid;
    if (c < NC){
      int m = c/DM, r = c - m*DM;
      const float* s = (m==0)?bq:((m==1)?bk:bv);
      bqkv[c] = s[r] * ((m==0)?SCALEQ:1.0f);
    }
  }
}

// ---------------- GEMM: C = A[M,K] * Bt[N,K]^T + bias ----------------
// EPI==0: Q,K row-major; V tiles (nt>=12) bounce through LDS -> V^T direct.
// EPI==1: plain fp32 store.
template<int BM, int EPI>
__global__ __launch_bounds__(256) void k_gemm(
    const __bf16* __restrict__ A, const __bf16* __restrict__ Bt,
    const float* __restrict__ bias, float* __restrict__ outF,
    __bf16* __restrict__ qb, __bf16* __restrict__ kb, __bf16* __restrict__ vt,
    int M, int N)
{
  constexpr int BN = 128, BK = 64;
  constexpr int K = DM;
  constexpr int HM = BM/2;
  constexpr int MR = BM/32;
  union ShmU {
    struct { __bf16 As[BM][BK]; __bf16 Bs[BN][BK]; } ab;
    __bf16 Vl[(EPI==0)?128:1][136];   // 34 KB bounce buffer (EPI==0 only)
  };
  __shared__ ShmU u;
  const int tid = threadIdx.x;
  const int w = tid>>6, lane = tid&63, g = lane>>4, r15 = lane&15;
  const int wr = w>>1, wc = w&1;
  const int nTM = M/BM;
  const int bx = xcd_swz(blockIdx.x, gridDim.x);
  const int mt = bx % nTM, nt = bx / nTM;
  const int m0 = mt*BM, n0 = nt*BN;

  const int rrel = lane>>3, seg = lane&7;
  const int ssrc = seg ^ rrel;            // XOR-swizzled source column

  f32x4 acc[MR][4];
  #pragma unroll
  for (int i=0;i<MR;i++)
    #pragma unroll
    for (int j=0;j<4;j++) acc[i][j] = f32x4{0.f,0.f,0.f,0.f};

  for (int k0=0;k0<K;k0+=BK){
#if HAS_GLDS
    #pragma unroll
    for (int c=0;c<BM/32;c++)
      glds16(&A[(size_t)(m0 + w*(BM/4) + c*8 + rrel)*K + k0 + ssrc*8],
             &u.ab.As[w*(BM/4) + c*8][0]);
    #pragma unroll
    for (int c=0;c<4;c++)
      glds16(&Bt[(size_t)(n0 + w*32 + c*8 + rrel)*K + k0 + ssrc*8],
             &u.ab.Bs[w*32 + c*8][0]);
#else
    #pragma unroll
    for (int c=0;c<BM/32;c++)
      *reinterpret_cast<uint4*>(&u.ab.As[w*(BM/4) + c*8 + rrel][seg*8]) =
        *reinterpret_cast<const uint4*>(&A[(size_t)(m0 + w*(BM/4) + c*8 + rrel)*K + k0 + ssrc*8]);
    #pragma unroll
    for (int c=0;c<4;c++)
      *reinterpret_cast<uint4*>(&u.ab.Bs[w*32 + c*8 + rrel][seg*8]) =
        *reinterpret_cast<const uint4*>(&Bt[(size_t)(n0 + w*32 + c*8 + rrel)*K + k0 + ssrc*8]);
#endif
    __syncthreads();
    bf16x8 af[MR][2], bfr[4][2];
    #pragma unroll
    for (int mi=0;mi<MR;mi++){
      int row = wr*HM + mi*16 + r15;
      #pragma unroll
      for (int c2=0;c2<2;c2++)
        af[mi][c2] = *reinterpret_cast<const bf16x8*>(&u.ab.As[row][8*((c2*4+g) ^ (row&7))]);
    }
    #pragma unroll
    for (int ni=0;ni<4;ni++){
      int row = wc*64 + ni*16 + r15;
      #pragma unroll
      for (int c2=0;c2<2;c2++)
        bfr[ni][c2] = *reinterpret_cast<const bf16x8*>(&u.ab.Bs[row][8*((c2*4+g) ^ (row&7))]);
    }
    #pragma unroll
    for (int c2=0;c2<2;c2++)
      #pragma unroll
      for (int mi=0;mi<MR;mi++)
        #pragma unroll
        for (int ni=0;ni<4;ni++)
          acc[mi][ni] = MFMA_16x16x32(af[mi][c2], bfr[ni][c2], acc[mi][ni]);
    __syncthreads();
  }

  if constexpr (EPI==0){
    if (nt >= 12){
      // ---- V^T epilogue: bounce tile through LDS, store [bh][e][t] ----
      #pragma unroll
      for (int mi=0;mi<MR;mi++){
        int rowl = wr*HM + mi*16 + 4*g;
        #pragma unroll
        for (int ni=0;ni<4;ni++){
          int coll = wc*64 + ni*16 + r15;
          float bc = bias[n0 + coll];
          bf16x4 vv;
          vv[0]=(__bf16)(acc[mi][ni][0]+bc); vv[1]=(__bf16)(acc[mi][ni][1]+bc);
          vv[2]=(__bf16)(acc[mi][ni][2]+bc); vv[3]=(__bf16)(acc[mi][ni][3]+bc);
          *reinterpret_cast<bf16x4*>(&u.Vl[coll][rowl]) = vv;
        }
      }
      __syncthreads();
      const int b = m0 >> 11, s0 = m0 & 2047;
      const int c2base = (nt - 12) * 128;
      #pragma unroll
      for (int p=0;p<8;p++){
        int chunk = p*256 + tid;
        int rowl = chunk >> 4, segl = chunk & 15;
        int c2 = c2base + rowl, hh = c2 >> 6, ee = c2 & 63;
        *reinterpret_cast<uint4*>(
            &vt[(((size_t)b*NH + hh)*HD + ee)*SS + s0 + segl*8]) =
          *reinterpret_cast<const uint4*>(&u.Vl[rowl][segl*8]);
      }
      return;
    }
  }

  #pragma unroll
  for (int mi=0;mi<MR;mi++){
    #pragma unroll
    for (int ni=0;ni<4;ni++){
      int row0 = m0 + wr*HM + mi*16 + 4*g;
      int col  = n0 + wc*64 + ni*16 + r15;
      float bc = bias[col];
      #pragma unroll
      for (int r=0;r<4;r++){
        float val = acc[mi][ni][r] + bc;
        int rr = row0 + r;
        if (EPI==1){
          outF[(size_t)rr*DM + col] = val;
        } else {
          int b = rr >> 11, s = rr & 2047;
          int m = col >= DM ? 1 : 0;   // only Q/K tiles reach here
          int c2 = col - m*DM, hh = c2>>6, ee = c2&63;
          __bf16* dst = (m==0) ? qb : kb;
          dst[(((size_t)b*NH + hh)*SS + s)*HD + ee] = (__bf16)val;
        }
      }
    }
  }
}

// ---------------- flash attention: TT=128, one barrier per 128 keys ----
// r22 ledger: attn chain-bound at 32 barrier-separated tiles. TT=128 halves
// the serial-chain count (16 iters); inner work stays in 64-wide half-passes
// reusing the same register blocks (kf[4][2] then vf[4][2] per half) so peak
// VGPR stays ~170 (r12 ran 188 clean). LDS 70KB -> 2 blocks/CU cap (measured
// residency ~1.5 anyway).
__global__ __launch_bounds__(256) void k_attn(
    const __bf16* __restrict__ Qb, const __bf16* __restrict__ Kb,
    const __bf16* __restrict__ Vt, __bf16* __restrict__ AO, int kvLen)
{
  constexpr int TT = 128, SK = 72, SV = 136;
  __shared__ __align__(16) __bf16 Ks[2][TT][SK];    // 2 x 18 KB
  __shared__ __align__(16) __bf16 Vs[2][HD][SV];    // 2 x 17 KB
  const int tid = threadIdx.x, w = tid>>6, lane = tid&63, g = lane>>4, r15 = lane&15;
  const int bx = xcd_swz(blockIdx.x, gridDim.x);
  const int qt = bx & 15, bh = bx >> 4;
  const int q0 = qt*128 + w*32;
  const __bf16* Qh = Qb + (size_t)bh*SS*HD;
  const __bf16* Kh = Kb + (size_t)bh*SS*HD;
  const __bf16* Vh = Vt + (size_t)bh*HD*SS;

  bf16x8 qf[2][2];
  #pragma unroll
  for (int sub=0; sub<2; sub++){
    int qrow = q0 + sub*16 + r15;
    qf[sub][0] = *reinterpret_cast<const bf16x8*>(&Qh[qrow*HD + g*8]);
    qf[sub][1] = *reinterpret_cast<const bf16x8*>(&Qh[qrow*HD + 32 + g*8]);
  }

  f32x4 o[2][4];
  #pragma unroll
  for (int s2=0;s2<2;s2++)
    #pragma unroll
    for (int i=0;i<4;i++) o[s2][i] = f32x4{0.f,0.f,0.f,0.f};
  float psum[2] = {0.f, 0.f};

  // staging geometry: K = 1024 chunks (row=c>>3, seg=c&7); V = 1024 chunks
  // (row=c>>4, seg=c&15); 4 chunks each per thread.
  const int krow = tid>>3, kseg = tid&7;
  const int vrow = tid>>4, vseg = tid&15;
  const int vhalf = vseg>>3, vs7 = vseg&7;
  const int vcol = vhalf*64 + 32*(vs7>>2) + 16*(vs7&1) + 4*((vs7>>1)&1);

  auto stageK = [&](int buf, int t0c, uint4* kv){
    #pragma unroll
    for (int i=0;i<4;i++)
      kv[i] = *reinterpret_cast<const uint4*>(&Kh[(size_t)(t0c + krow + 32*i)*HD + kseg*8]);
    (void)buf;
  };
  auto writeK = [&](int buf, uint4* kv){
    #pragma unroll
    for (int i=0;i<4;i++)
      *reinterpret_cast<uint4*>(&Ks[buf][krow + 32*i][kseg*8]) = kv[i];
  };
  auto stageV = [&](int t0c, uint4* vv){
    #pragma unroll
    for (int i=0;i<4;i++)
      vv[i] = *reinterpret_cast<const uint4*>(&Vh[(size_t)(vrow + 16*i)*SS + t0c + vseg*8]);
  };
  auto writeV = [&](int buf, uint4* vv){
    #pragma unroll
    for (int i=0;i<4;i++){
      *reinterpret_cast<uint2*>(&Vs[buf][vrow + 16*i][vcol])     = uint2{vv[i].x, vv[i].y};
      *reinterpret_cast<uint2*>(&Vs[buf][vrow + 16*i][vcol + 8]) = uint2{vv[i].z, vv[i].w};
    }
  };

  { // prologue: stage tile 0 into buffer 0
    uint4 kv[4], vv[4];
    stageK(0, 0, kv); stageV(0, vv);
    writeK(0, kv);    writeV(0, vv);
  }
  __syncthreads();

  int cur = 0;
  for (int t0 = 0; t0 < kvLen; t0 += TT){
    const bool hasNext = (t0 + TT) < kvLen;
    uint4 kvn[4], vvn[4];
    if (hasNext){ stageK(cur^1, t0+TT, kvn); stageV(t0+TT, vvn); }

    // ---- QK^T + exp, per 64-key half (kf regs reused across halves) ----
    bf16x4 pa[2][8];
    #pragma unroll
    for (int h2=0; h2<2; h2++){
      bf16x8 kf0[4], kf1[4];
      #pragma unroll
      for (int jt=0;jt<4;jt++){
        kf0[jt] = *reinterpret_cast<const bf16x8*>(&Ks[cur][h2*64 + jt*16 + r15][g*8]);
        kf1[jt] = *reinterpret_cast<const bf16x8*>(&Ks[cur][h2*64 + jt*16 + r15][32 + g*8]);
      }
      f32x4 sc[2][4];
      __builtin_amdgcn_s_setprio(1);
      #pragma unroll
      for (int sub=0; sub<2; sub++)
        #pragma unroll
        for (int jt=0;jt<4;jt++){
          f32x4 t = f32x4{0.f,0.f,0.f,0.f};
          t = MFMA_16x16x32(kf0[jt], qf[sub][0], t);
          t = MFMA_16x16x32(kf1[jt], qf[sub][1], t);
          sc[sub][jt] = t;
        }
      __builtin_amdgcn_s_setprio(0);
      #pragma unroll
      for (int sub=0; sub<2; sub++)
        #pragma unroll
        for (int ks=0;ks<4;ks++){
          float p0 = EXP2(sc[sub][ks][0]);
          float p1 = EXP2(sc[sub][ks][1]);
          float p2 = EXP2(sc[sub][ks][2]);
          float p3 = EXP2(sc[sub][ks][3]);
          pa[sub][h2*4+ks][0] = (__bf16)p0; pa[sub][h2*4+ks][1] = (__bf16)p1;
          pa[sub][h2*4+ks][2] = (__bf16)p2; pa[sub][h2*4+ks][3] = (__bf16)p3;
          psum[sub] += (p0 + p1) + (p2 + p3);
        }
    }

    // ---- PV, per 64-key half (vf regs reused across halves) ----
    #pragma unroll
    for (int h2=0; h2<2; h2++){
      bf16x8 vf[4][2];
      #pragma unroll
      for (int et=0;et<4;et++)
        #pragma unroll
        for (int p=0;p<2;p++)
          vf[et][p] = *reinterpret_cast<const bf16x8*>(&Vs[cur][et*16 + r15][h2*64 + p*32 + g*8]);
      __builtin_amdgcn_s_setprio(1);
      #pragma unroll
      for (int sub=0; sub<2; sub++)
        #pragma unroll
        for (int et=0;et<4;et++)
          #pragma unroll
          for (int ks=0;ks<4;ks++){
            bf16x8 vv = vf[et][ks>>1];
            bf16x4 vq = (ks & 1) ? bf16x4{vv[4],vv[5],vv[6],vv[7]}
                                 : bf16x4{vv[0],vv[1],vv[2],vv[3]};
            o[sub][et] = MFMA16(pa[sub][h2*4+ks], vq, o[sub][et]);
          }
      __builtin_amdgcn_s_setprio(0);
    }

    if (hasNext){ writeK(cur^1, kvn); writeV(cur^1, vvn); }
    __syncthreads();               // ONE barrier per 128 keys
    cur ^= 1;
  }

  const int b = bh/NH, h = bh - b*NH;
  #pragma unroll
  for (int sub=0; sub<2; sub++){
    float lv = psum[sub];
    lv += __shfl_xor(lv, 16);
    lv += __shfl_xor(lv, 32);
    float linv = 1.0f / lv;
    float li[4];
    #pragma unroll
    for (int r=0;r<4;r++) li[r] = __shfl(linv, 4*g + r);
    #pragma unroll
    for (int r=0;r<4;r++){
      int s = q0 + sub*16 + 4*g + r;
      #pragma unroll
      for (int et=0;et<4;et++)
        AO[((size_t)(b*SS + s))*DM + h*HD + et*16 + r15] = (__bf16)(o[sub][et][r]*li[r]);
    }
  }
}

// ---------------- launch ----------------
extern "C" void kernel_launch(void* const* d_in, const int* in_sizes, int n_in,
                              void* d_out, int out_size, void* d_ws, size_t ws_size,
                              hipStream_t stream) {
  const float* x  = (const float*)d_in[0];
  const float* Wq = (const float*)d_in[1];
  const float* Wk = (const float*)d_in[2];
  const float* Wv = (const float*)d_in[3];
  const float* bq = (const float*)d_in[4];
  const float* bk = (const float*)d_in[5];
  const float* bv = (const float*)d_in[6];
  const float* Wo = (const float*)d_in[7];
  const float* bo = (const float*)d_in[8];
  float* out = (float*)d_out;

  char* ws = (char*)d_ws;
  size_t off = 0;
  auto alloc = [&](size_t bytes) -> void* {
    void* p = ws + off;
    off += (bytes + 255) & ~size_t(255);
    return p;
  };
  __bf16* xb   = (__bf16*)alloc((size_t)NR*DM*2);
  __bf16* wt   = (__bf16*)alloc((size_t)NC*DM*2);
  float*  bqkv = (float*) alloc((size_t)NC*4);
  __bf16* wot  = (__bf16*)alloc((size_t)DM*DM*2);
  __bf16* qb2  = (__bf16*)alloc((size_t)BB*NH*SS*HD*2);
  __bf16* kb2  = (__bf16*)alloc((size_t)BB*NH*SS*HD*2);
  __bf16* vt2  = (__bf16*)alloc((size_t)BB*NH*SS*HD*2);   // V transposed (direct)
  __bf16* aob  = (__bf16*)alloc((size_t)NR*DM*2);

  k_prep<<<PB_X + PB_W + PB_O + PB_B, 256, 0, stream>>>(
      x, Wq, Wk, Wv, bq, bk, bv, Wo, xb, wt, wot, bqkv);

  // QKV GEMM writes Q,K row-major and V^T directly (LDS-bounce epilogue)
  k_gemm<128,0><<<(NR/128)*(NC/128), 256, 0, stream>>>(
      xb, wt, bqkv, nullptr, qb2, kb2, vt2, NR, NC);

  // nsplit=1: direct bf16 store, no partials, no merge kernel
  k_attn<<<BB*NH*(SS/128), 256, 0, stream>>>(qb2, kb2, vt2, aob, SS);

  k_gemm<64,1><<<(NR/64)*(DM/128), 256, 0, stream>>>(
      aob, wot, bo, out, nullptr, nullptr, nullptr, NR, DM);
}

// Round 24
// 113.714 us; speedup vs baseline: 1.1145x; 1.1145x over previous
//
#include <hip/hip_runtime.h>
#include <hip/hip_bf16.h>

typedef __bf16 bf16x8 __attribute__((ext_vector_type(8)));
typedef __bf16 bf16x4 __attribute__((ext_vector_type(4)));
typedef float  f32x4  __attribute__((ext_vector_type(4)));
typedef short  short4v __attribute__((ext_vector_type(4)));

#define MFMA_16x16x32(a,b,c) __builtin_amdgcn_mfma_f32_16x16x32_bf16((a),(b),(c),0,0,0)

#if __has_builtin(__builtin_amdgcn_mfma_f32_16x16x16_bf16)
__device__ inline f32x4 MFMA16(bf16x4 a, bf16x4 b, f32x4 c){
  return __builtin_amdgcn_mfma_f32_16x16x16_bf16(a, b, c, 0, 0, 0);
}
#elif __has_builtin(__builtin_amdgcn_mfma_f32_16x16x16bf16_1k)
__device__ inline f32x4 MFMA16(bf16x4 a, bf16x4 b, f32x4 c){
  return __builtin_amdgcn_mfma_f32_16x16x16bf16_1k(
      __builtin_bit_cast(short4v, a), __builtin_bit_cast(short4v, b), c, 0, 0, 0);
}
#else
__device__ inline f32x4 MFMA16(bf16x4 a, bf16x4 b, f32x4 c){
  f32x4 d;
  asm volatile("v_mfma_f32_16x16x16_bf16 %0, %1, %2, %3"
               : "=v"(d) : "v"(a), "v"(b), "v"(c));
  return d;
}
#endif

// raw hardware exp2 (r13: libm exp2f was ~half of attn VALU)
#if __has_builtin(__builtin_amdgcn_exp2f)
#define EXP2(x) __builtin_amdgcn_exp2f(x)
#else
extern "C" __device__ float __ocml_native_exp2_f32(float);
#define EXP2(x) __ocml_native_exp2_f32(x)
#endif

#if __has_builtin(__builtin_amdgcn_global_load_lds)
#define HAS_GLDS 1
__device__ inline void glds16(const __bf16* g, __bf16* l){
  __builtin_amdgcn_global_load_lds(
      (const __attribute__((address_space(1))) unsigned int*)g,
      (__attribute__((address_space(3))) unsigned int*)l, 16, 0, 0);
}
#else
#define HAS_GLDS 0
#endif

static constexpr int DM = 768;
static constexpr int NH = 12;
static constexpr int HD = 64;
static constexpr int BB = 2;
static constexpr int SS = 2048;
static constexpr int NR = BB*SS;       // 4096 rows (b,s)
static constexpr int NC = 3*DM;        // 2304 qkv output cols
// logits in log2 domain: fold 1/sqrt(64) * log2(e) into Wq,bq
static constexpr float SCALEQ = 0.125f * 1.4426950408889634f;

__device__ inline int xcd_swz(int b, int n){
  return (n % 8 == 0) ? (b % 8) * (n >> 3) + (b >> 3) : b;
}

// ---------------- fused prep kernel (one launch) -----------
static constexpr int PB_X = NR*DM/(4*256);   // 3072
static constexpr int PB_W = 3*12*12;         // 432
static constexpr int PB_O = 12*12;           // 144
static constexpr int PB_B = (NC+255)/256;    // 9
__global__ __launch_bounds__(256) void k_prep(const float* __restrict__ x,
    const float* __restrict__ Wq, const float* __restrict__ Wk,
    const float* __restrict__ Wv, const float* __restrict__ bq,
    const float* __restrict__ bk, const float* __restrict__ bv,
    const float* __restrict__ Wo,
    __bf16* __restrict__ xb, __bf16* __restrict__ Wt,
    __bf16* __restrict__ WoT, float* __restrict__ bqkv)
{
  __shared__ float tile[64][65];
  const int blk = blockIdx.x, tid = threadIdx.x;
  if (blk < PB_X){
    int i = blk*256 + tid;
    float4 v = reinterpret_cast<const float4*>(x)[i];
    bf16x4 o; o[0]=(__bf16)v.x; o[1]=(__bf16)v.y; o[2]=(__bf16)v.z; o[3]=(__bf16)v.w;
    reinterpret_cast<bf16x4*>(xb)[i] = o;
  } else if (blk < PB_X + PB_W){
    int b2 = blk - PB_X;
    int dt = b2 % 12, h = (b2/12) % 12, m = b2/144;
    const float* W = (m==0)?Wq:((m==1)?Wk:Wv);
    float scale = (m==0)?SCALEQ:1.0f;
    int tx = tid & 63, ty = tid >> 6;
    #pragma unroll
    for (int i=0;i<16;i++){
      int dl = ty*16+i;
      tile[dl][tx] = W[(h*DM + dt*64 + dl)*HD + tx];
    }
    __syncthreads();
    #pragma unroll
    for (int i=0;i<16;i++){
      int e = ty*16+i;
      Wt[(size_t)(m*DM + h*HD + e)*DM + dt*64 + tx] = (__bf16)(tile[tx][e]*scale);
    }
  } else if (blk < PB_X + PB_W + PB_O){
    int b2 = blk - PB_X - PB_W;
    int dt = b2 % 12, ct = b2/12;
    int tx = tid & 63, ty = tid >> 6;
    #pragma unroll
    for (int i=0;i<16;i++){
      int dl = ty*16+i;
      tile[dl][tx] = Wo[(dt*64+dl)*DM + ct*64 + tx];
    }
    __syncthreads();
    #pragma unroll
    for (int i=0;i<16;i++){
      int cl = ty*16+i;
      WoT[(size_t)(ct*64+cl)*DM + dt*64 + tx] = (__bf16)tile[tx][cl];
    }
  } else {
    int c = (blk - PB_X - PB_W - PB_O)*256 + tid;
    if (c < NC){
      int m = c/DM, r = c - m*DM;
      const float* s = (m==0)?bq:((m==1)?bk:bv);
      bqkv[c] = s[r] * ((m==0)?SCALEQ:1.0f);
    }
  }
}

// ---------------- GEMM: C = A[M,K] * Bt[N,K]^T + bias ----------------
// EPI==0: Q,K row-major; V tiles (nt>=12, block-uniform) bounce the output
//         tile through LDS and store V^T [bh][e][t] with 256B runs directly.
// EPI==1: plain fp32 store.
template<int BM, int EPI>
__global__ __launch_bounds__(256) void k_gemm(
    const __bf16* __restrict__ A, const __bf16* __restrict__ Bt,
    const float* __restrict__ bias, float* __restrict__ outF,
    __bf16* __restrict__ qb, __bf16* __restrict__ kb, __bf16* __restrict__ vt,
    int M, int N)
{
  constexpr int BN = 128, BK = 64;
  constexpr int K = DM;
  constexpr int HM = BM/2;
  constexpr int MR = BM/32;
  union ShmU {
    struct { __bf16 As[BM][BK]; __bf16 Bs[BN][BK]; } ab;
    __bf16 Vl[(EPI==0)?128:1][136];   // 34 KB bounce buffer (EPI==0 only)
  };
  __shared__ ShmU u;
  const int tid = threadIdx.x;
  const int w = tid>>6, lane = tid&63, g = lane>>4, r15 = lane&15;
  const int wr = w>>1, wc = w&1;
  const int nTM = M/BM;
  const int bx = xcd_swz(blockIdx.x, gridDim.x);
  const int mt = bx % nTM, nt = bx / nTM;
  const int m0 = mt*BM, n0 = nt*BN;

  const int rrel = lane>>3, seg = lane&7;
  const int ssrc = seg ^ rrel;            // XOR-swizzled source column

  f32x4 acc[MR][4];
  #pragma unroll
  for (int i=0;i<MR;i++)
    #pragma unroll
    for (int j=0;j<4;j++) acc[i][j] = f32x4{0.f,0.f,0.f,0.f};

  for (int k0=0;k0<K;k0+=BK){
#if HAS_GLDS
    #pragma unroll
    for (int c=0;c<BM/32;c++)
      glds16(&A[(size_t)(m0 + w*(BM/4) + c*8 + rrel)*K + k0 + ssrc*8],
             &u.ab.As[w*(BM/4) + c*8][0]);
    #pragma unroll
    for (int c=0;c<4;c++)
      glds16(&Bt[(size_t)(n0 + w*32 + c*8 + rrel)*K + k0 + ssrc*8],
             &u.ab.Bs[w*32 + c*8][0]);
#else
    #pragma unroll
    for (int c=0;c<BM/32;c++)
      *reinterpret_cast<uint4*>(&u.ab.As[w*(BM/4) + c*8 + rrel][seg*8]) =
        *reinterpret_cast<const uint4*>(&A[(size_t)(m0 + w*(BM/4) + c*8 + rrel)*K + k0 + ssrc*8]);
    #pragma unroll
    for (int c=0;c<4;c++)
      *reinterpret_cast<uint4*>(&u.ab.Bs[w*32 + c*8 + rrel][seg*8]) =
        *reinterpret_cast<const uint4*>(&Bt[(size_t)(n0 + w*32 + c*8 + rrel)*K + k0 + ssrc*8]);
#endif
    __syncthreads();
    bf16x8 af[MR][2], bfr[4][2];
    #pragma unroll
    for (int mi=0;mi<MR;mi++){
      int row = wr*HM + mi*16 + r15;
      #pragma unroll
      for (int c2=0;c2<2;c2++)
        af[mi][c2] = *reinterpret_cast<const bf16x8*>(&u.ab.As[row][8*((c2*4+g) ^ (row&7))]);
    }
    #pragma unroll
    for (int ni=0;ni<4;ni++){
      int row = wc*64 + ni*16 + r15;
      #pragma unroll
      for (int c2=0;c2<2;c2++)
        bfr[ni][c2] = *reinterpret_cast<const bf16x8*>(&u.ab.Bs[row][8*((c2*4+g) ^ (row&7))]);
    }
    #pragma unroll
    for (int c2=0;c2<2;c2++)
      #pragma unroll
      for (int mi=0;mi<MR;mi++)
        #pragma unroll
        for (int ni=0;ni<4;ni++)
          acc[mi][ni] = MFMA_16x16x32(af[mi][c2], bfr[ni][c2], acc[mi][ni]);
    __syncthreads();
  }

  if constexpr (EPI==0){
    if (nt >= 12){
      // ---- V^T epilogue: bounce tile through LDS, store [bh][e][t] ----
      #pragma unroll
      for (int mi=0;mi<MR;mi++){
        int rowl = wr*HM + mi*16 + 4*g;
        #pragma unroll
        for (int ni=0;ni<4;ni++){
          int coll = wc*64 + ni*16 + r15;
          float bc = bias[n0 + coll];
          bf16x4 vv;
          vv[0]=(__bf16)(acc[mi][ni][0]+bc); vv[1]=(__bf16)(acc[mi][ni][1]+bc);
          vv[2]=(__bf16)(acc[mi][ni][2]+bc); vv[3]=(__bf16)(acc[mi][ni][3]+bc);
          *reinterpret_cast<bf16x4*>(&u.Vl[coll][rowl]) = vv;
        }
      }
      __syncthreads();
      const int b = m0 >> 11, s0 = m0 & 2047;
      const int c2base = (nt - 12) * 128;
      #pragma unroll
      for (int p=0;p<8;p++){
        int chunk = p*256 + tid;
        int rowl = chunk >> 4, segl = chunk & 15;
        int c2 = c2base + rowl, hh = c2 >> 6, ee = c2 & 63;
        *reinterpret_cast<uint4*>(
            &vt[(((size_t)b*NH + hh)*HD + ee)*SS + s0 + segl*8]) =
          *reinterpret_cast<const uint4*>(&u.Vl[rowl][segl*8]);
      }
      return;
    }
  }

  #pragma unroll
  for (int mi=0;mi<MR;mi++){
    #pragma unroll
    for (int ni=0;ni<4;ni++){
      int row0 = m0 + wr*HM + mi*16 + 4*g;
      int col  = n0 + wc*64 + ni*16 + r15;
      float bc = bias[col];
      #pragma unroll
      for (int r=0;r<4;r++){
        float val = acc[mi][ni][r] + bc;
        int rr = row0 + r;
        if (EPI==1){
          outF[(size_t)rr*DM + col] = val;
        } else {
          int b = rr >> 11, s = rr & 2047;
          int m = col >= DM ? 1 : 0;   // only Q/K tiles reach here
          int c2 = col - m*DM, hh = c2>>6, ee = c2&63;
          __bf16* dst = (m==0) ? qb : kb;
          dst[(((size_t)b*NH + hh)*SS + s)*HD + ee] = (__bf16)val;
        }
      }
    }
  }
}

// ---------------- flash attention (best config: dbuf TT=64, nsplit=1) ----
__global__ __launch_bounds__(256) void k_attn(
    const __bf16* __restrict__ Qb, const __bf16* __restrict__ Kb,
    const __bf16* __restrict__ Vt, __bf16* __restrict__ AO, int kvLen)
{
  constexpr int TT = 64, SK = 72;
  __shared__ __align__(16) __bf16 Ks[2][TT][SK];
  __shared__ __align__(16) __bf16 Vs[2][HD][SK];
  const int tid = threadIdx.x, w = tid>>6, lane = tid&63, g = lane>>4, r15 = lane&15;
  const int bx = xcd_swz(blockIdx.x, gridDim.x);
  const int qt = bx & 15, bh = bx >> 4;
  const int q0 = qt*128 + w*32;
  const int kv0 = 0;
  const __bf16* Qh = Qb + (size_t)bh*SS*HD;
  const __bf16* Kh = Kb + (size_t)bh*SS*HD;
  const __bf16* Vh = Vt + (size_t)bh*HD*SS;

  bf16x8 qf[2][2];
  #pragma unroll
  for (int sub=0; sub<2; sub++){
    int qrow = q0 + sub*16 + r15;
    qf[sub][0] = *reinterpret_cast<const bf16x8*>(&Qh[qrow*HD + g*8]);
    qf[sub][1] = *reinterpret_cast<const bf16x8*>(&Qh[qrow*HD + 32 + g*8]);
  }

  f32x4 o[2][4];
  #pragma unroll
  for (int s2=0;s2<2;s2++)
    #pragma unroll
    for (int i=0;i<4;i++) o[s2][i] = f32x4{0.f,0.f,0.f,0.f};
  float psum[2] = {0.f, 0.f};

  const int row0 = tid>>3,        seg0 = tid&7;
  const int row1 = (tid+256)>>3,  seg1 = tid&7;
  const int vcol0 = 32*(seg0>>2) + 16*(seg0&1) + 4*((seg0>>1)&1);

  { // prologue: stage tile 0 into buffer 0
    uint4 k0v = *reinterpret_cast<const uint4*>(&Kh[(kv0+row0)*HD + seg0*8]);
    uint4 k1v = *reinterpret_cast<const uint4*>(&Kh[(kv0+row1)*HD + seg1*8]);
    uint4 v0v = *reinterpret_cast<const uint4*>(&Vh[(size_t)row0*SS + kv0 + seg0*8]);
    uint4 v1v = *reinterpret_cast<const uint4*>(&Vh[(size_t)row1*SS + kv0 + seg1*8]);
    *reinterpret_cast<uint4*>(&Ks[0][row0][seg0*8]) = k0v;
    *reinterpret_cast<uint4*>(&Ks[0][row1][seg1*8]) = k1v;
    *reinterpret_cast<uint2*>(&Vs[0][row0][vcol0])     = uint2{v0v.x, v0v.y};
    *reinterpret_cast<uint2*>(&Vs[0][row0][vcol0 + 8]) = uint2{v0v.z, v0v.w};
    *reinterpret_cast<uint2*>(&Vs[0][row1][vcol0])     = uint2{v1v.x, v1v.y};
    *reinterpret_cast<uint2*>(&Vs[0][row1][vcol0 + 8]) = uint2{v1v.z, v1v.w};
  }
  __syncthreads();

  int cur = 0;
  for (int t0 = kv0; t0 < kv0 + kvLen; t0 += TT){
    const bool hasNext = (t0 + TT) < kv0 + kvLen;
    uint4 k0v, k1v, v0v, v1v;
    if (hasNext){   // issue next-tile global loads early
      k0v = *reinterpret_cast<const uint4*>(&Kh[(t0+TT+row0)*HD + seg0*8]);
      k1v = *reinterpret_cast<const uint4*>(&Kh[(t0+TT+row1)*HD + seg1*8]);
      v0v = *reinterpret_cast<const uint4*>(&Vh[(size_t)row0*SS + t0+TT + seg0*8]);
      v1v = *reinterpret_cast<const uint4*>(&Vh[(size_t)row1*SS + t0+TT + seg1*8]);
    }

    bf16x8 kf0[4], kf1[4];
    #pragma unroll
    for (int jt=0;jt<4;jt++){
      kf0[jt] = *reinterpret_cast<const bf16x8*>(&Ks[cur][jt*16 + r15][g*8]);
      kf1[jt] = *reinterpret_cast<const bf16x8*>(&Ks[cur][jt*16 + r15][32 + g*8]);
    }
    bf16x8 vf[4][2];
    #pragma unroll
    for (int et=0;et<4;et++)
      #pragma unroll
      for (int p=0;p<2;p++)
        vf[et][p] = *reinterpret_cast<const bf16x8*>(&Vs[cur][et*16 + r15][p*32 + g*8]);

    // QK^T swapped: sc[sub][jt] = D[k=4g+r (within jt*16)][q=r15]
    f32x4 sc[2][4];
    __builtin_amdgcn_s_setprio(1);
    #pragma unroll
    for (int sub=0; sub<2; sub++)
      #pragma unroll
      for (int jt=0;jt<4;jt++){
        f32x4 t = f32x4{0.f,0.f,0.f,0.f};
        t = MFMA_16x16x32(kf0[jt], qf[sub][0], t);
        t = MFMA_16x16x32(kf1[jt], qf[sub][1], t);
        sc[sub][jt] = t;
      }
    __builtin_amdgcn_s_setprio(0);

    // no-max softmax: P = exp2(sc), raw v_exp_f32; l accumulated in f32
    bf16x4 pa[2][4];
    #pragma unroll
    for (int sub=0; sub<2; sub++)
      #pragma unroll
      for (int ks=0;ks<4;ks++){
        float p0 = EXP2(sc[sub][ks][0]);
        float p1 = EXP2(sc[sub][ks][1]);
        float p2 = EXP2(sc[sub][ks][2]);
        float p3 = EXP2(sc[sub][ks][3]);
        pa[sub][ks][0] = (__bf16)p0; pa[sub][ks][1] = (__bf16)p1;
        pa[sub][ks][2] = (__bf16)p2; pa[sub][ks][3] = (__bf16)p3;
        psum[sub] += (p0 + p1) + (p2 + p3);
      }

    // PV (register-resident)
    __builtin_amdgcn_s_setprio(1);
    #pragma unroll
    for (int sub=0; sub<2; sub++)
      #pragma unroll
      for (int et=0;et<4;et++)
        #pragma unroll
        for (int ks=0;ks<4;ks++){
          bf16x8 vv = vf[et][ks>>1];
          bf16x4 vq = (ks & 1) ? bf16x4{vv[4],vv[5],vv[6],vv[7]}
                               : bf16x4{vv[0],vv[1],vv[2],vv[3]};
          o[sub][et] = MFMA16(pa[sub][ks], vq, o[sub][et]);
        }
    __builtin_amdgcn_s_setprio(0);

    if (hasNext){   // LDS write to other buffer (global latency hidden above)
      int nxt = cur ^ 1;
      *reinterpret_cast<uint4*>(&Ks[nxt][row0][seg0*8]) = k0v;
      *reinterpret_cast<uint4*>(&Ks[nxt][row1][seg1*8]) = k1v;
      *reinterpret_cast<uint2*>(&Vs[nxt][row0][vcol0])     = uint2{v0v.x, v0v.y};
      *reinterpret_cast<uint2*>(&Vs[nxt][row0][vcol0 + 8]) = uint2{v0v.z, v0v.w};
      *reinterpret_cast<uint2*>(&Vs[nxt][row1][vcol0])     = uint2{v1v.x, v1v.y};
      *reinterpret_cast<uint2*>(&Vs[nxt][row1][vcol0 + 8]) = uint2{v1v.z, v1v.w};
    }
    __syncthreads();               // single barrier per tile
    cur ^= 1;
  }

  const int b = bh/NH, h = bh - b*NH;
  #pragma unroll
  for (int sub=0; sub<2; sub++){
    float lv = psum[sub];
    lv += __shfl_xor(lv, 16);
    lv += __shfl_xor(lv, 32);
    float linv = 1.0f / lv;
    float li[4];
    #pragma unroll
    for (int r=0;r<4;r++) li[r] = __shfl(linv, 4*g + r);
    #pragma unroll
    for (int r=0;r<4;r++){
      int s = q0 + sub*16 + 4*g + r;
      #pragma unroll
      for (int et=0;et<4;et++)
        AO[((size_t)(b*SS + s))*DM + h*HD + et*16 + r15] = (__bf16)(o[sub][et][r]*li[r]);
    }
  }
}

// ---------------- launch ----------------
extern "C" void kernel_launch(void* const* d_in, const int* in_sizes, int n_in,
                              void* d_out, int out_size, void* d_ws, size_t ws_size,
                              hipStream_t stream) {
  const float* x  = (const float*)d_in[0];
  const float* Wq = (const float*)d_in[1];
  const float* Wk = (const float*)d_in[2];
  const float* Wv = (const float*)d_in[3];
  const float* bq = (const float*)d_in[4];
  const float* bk = (const float*)d_in[5];
  const float* bv = (const float*)d_in[6];
  const float* Wo = (const float*)d_in[7];
  const float* bo = (const float*)d_in[8];
  float* out = (float*)d_out;

  char* ws = (char*)d_ws;
  size_t off = 0;
  auto alloc = [&](size_t bytes) -> void* {
    void* p = ws + off;
    off += (bytes + 255) & ~size_t(255);
    return p;
  };
  __bf16* xb   = (__bf16*)alloc((size_t)NR*DM*2);
  __bf16* wt   = (__bf16*)alloc((size_t)NC*DM*2);
  float*  bqkv = (float*) alloc((size_t)NC*4);
  __bf16* wot  = (__bf16*)alloc((size_t)DM*DM*2);
  __bf16* qb2  = (__bf16*)alloc((size_t)BB*NH*SS*HD*2);
  __bf16* kb2  = (__bf16*)alloc((size_t)BB*NH*SS*HD*2);
  __bf16* vt2  = (__bf16*)alloc((size_t)BB*NH*SS*HD*2);   // V transposed (direct)
  __bf16* aob  = (__bf16*)alloc((size_t)NR*DM*2);

  k_prep<<<PB_X + PB_W + PB_O + PB_B, 256, 0, stream>>>(
      x, Wq, Wk, Wv, bq, bk, bv, Wo, xb, wt, wot, bqkv);

  // QKV GEMM writes Q,K row-major and V^T directly (LDS-bounce epilogue)
  k_gemm<128,0><<<(NR/128)*(NC/128), 256, 0, stream>>>(
      xb, wt, bqkv, nullptr, qb2, kb2, vt2, NR, NC);

  // nsplit=1: direct bf16 store, no partials, no merge kernel
  k_attn<<<BB*NH*(SS/128), 256, 0, stream>>>(qb2, kb2, vt2, aob, SS);

  k_gemm<64,1><<<(NR/64)*(DM/128), 256, 0, stream>>>(
      aob, wot, bo, out, nullptr, nullptr, nullptr, NR, DM);
}